// Round 10
// baseline (171.126 us; speedup 1.0000x reference)
//
#include <hip/hip_runtime.h>
#include <hip/hip_bf16.h>

#define NB 4
#define NT 1024
#define ND 512
#define NH 8
#define NKC 64

typedef __bf16 bf16x8 __attribute__((ext_vector_type(8)));
typedef float f32x4 __attribute__((ext_vector_type(4)));

__device__ __forceinline__ f32x4 MFMA(bf16x8 a, bf16x8 b, f32x4 c) {
    return __builtin_amdgcn_mfma_f32_16x16x32_bf16(a, b, c, 0, 0, 0);
}
__device__ __forceinline__ unsigned short f2bu(float v) {
    __hip_bfloat16 b = __float2bfloat16(v);
    return *(unsigned short*)&b;
}
__device__ __forceinline__ void split1(float v, unsigned short& h, unsigned short& l)
{
    __hip_bfloat16 hb = __float2bfloat16(v);
    float r = v - __bfloat162float(hb);
    __hip_bfloat16 lb = __float2bfloat16(r);
    h = *(unsigned short*)&hb;
    l = *(unsigned short*)&lb;
}
__device__ __forceinline__ void splitpack(const float4 a, const float4 b, uint4& h, uint4& l)
{
    union { unsigned short u[8]; uint4 v; } H, L;
    const float f[8] = {a.x, a.y, a.z, a.w, b.x, b.y, b.z, b.w};
    #pragma unroll
    for (int j = 0; j < 8; ++j) split1(f[j], H.u[j], L.u[j]);
    h = H.v; l = L.v;
}

// w[k][n] fp32 -> wT hi/lo bf16 [n][k]
__global__ __launch_bounds__(256)
void splitT_kernel(const float* __restrict__ w0, const float* __restrict__ w1,
                   const float* __restrict__ w2, const float* __restrict__ w3,
                   unsigned short* __restrict__ wT)
{
    __shared__ float tl[32][33];
    const float* w = (blockIdx.z == 0) ? w0 : (blockIdx.z == 1) ? w1
                   : (blockIdx.z == 2) ? w2 : w3;
    unsigned short* hi = wT + (size_t)blockIdx.z * 2 * (ND * ND);
    unsigned short* lo = hi + ND * ND;
    const int t = threadIdx.x;
    const int x0 = blockIdx.x * 32, y0 = blockIdx.y * 32;
    {
        const int r = t >> 3, c = (t & 7) * 4;
        const float4 v = *(const float4*)&w[(size_t)(y0 + r) * ND + x0 + c];
        tl[r][c] = v.x; tl[r][c+1] = v.y; tl[r][c+2] = v.z; tl[r][c+3] = v.w;
    }
    __syncthreads();
    {
        const int nr = t >> 3, k4 = (t & 7) * 4;
        unsigned short hh[4], ll[4];
        #pragma unroll
        for (int j = 0; j < 4; ++j) split1(tl[k4 + j][nr], hh[j], ll[j]);
        ushort4 h = make_ushort4(hh[0], hh[1], hh[2], hh[3]);
        ushort4 l = make_ushort4(ll[0], ll[1], ll[2], ll[3]);
        *(ushort4*)&hi[(size_t)(x0 + nr) * ND + y0 + k4] = h;
        *(ushort4*)&lo[(size_t)(x0 + nr) * ND + y0 + k4] = l;
    }
}

// ===========================================================================
// Projections: 64(m) x 128(n) tile, BK=32. q -> hi/lo [bh][t][kc];
// k -> bf16 [bh][t][kc]; v -> bf16 TILED [bh][t>>6][kc][t&63].
// v-GEMM uses single-bf16 weights (drops ah*bl term).
// ===========================================================================
__global__ __launch_bounds__(256, 3)
void proj_mfma(const float* __restrict__ x, const float* __restrict__ cc,
               const unsigned short* __restrict__ wT,
               const float* __restrict__ bq, const float* __restrict__ bk,
               const float* __restrict__ bv,
               unsigned short* __restrict__ qh_o, unsigned short* __restrict__ ql_o,
               unsigned short* __restrict__ kh_o, unsigned short* __restrict__ vh_o)
{
    __shared__ unsigned short smem[12288];           // 24 KB
    unsigned short* Ah = smem;                       // 64*32
    unsigned short* Al = smem + 2048;                // 64*32
    unsigned short* Bh = smem + 4096;                // 128*32
    unsigned short* Bl = smem + 8192;                // 128*32
    unsigned short* Tr = smem;                       // alias: 256*40 = 10240

    const int which = blockIdx.z;
    const float* A_g = (which == 0) ? x : cc;
    const unsigned short* Bh_g = wT + (size_t)which * 2 * (ND * ND);
    const unsigned short* Bl_g = Bh_g + ND * ND;
    const float* bias = (which == 0) ? bq : (which == 1) ? bk : bv;

    const int tid = threadIdx.x, l = tid & 63, w = tid >> 6;
    const int quad = l >> 4, lc = l & 15;
    const int wm = w & 1, wn = w >> 1;
    const int n0 = blockIdx.x * 128, m0 = blockIdx.y * 64;

    const int am = tid >> 2, ak = (tid & 3) * 8;
    const size_t aG = (size_t)(m0 + am) * ND + ak;
    const int bn = tid >> 1, bk2 = (tid & 1) * 16;
    const size_t bG = (size_t)(n0 + bn) * ND + bk2;

    float4 ra0 = *(const float4*)&A_g[aG];
    float4 ra1 = *(const float4*)&A_g[aG + 4];
    uint4 rb0 = *(const uint4*)&Bh_g[bG];
    uint4 rb1 = *(const uint4*)&Bh_g[bG + 8];
    uint4 rb2 = {}, rb3 = {};
    if (which != 2) {
        rb2 = *(const uint4*)&Bl_g[bG];
        rb3 = *(const uint4*)&Bl_g[bG + 8];
    }

    f32x4 acc[2][4];
    #pragma unroll
    for (int mi = 0; mi < 2; ++mi)
        #pragma unroll
        for (int ni = 0; ni < 4; ++ni) acc[mi][ni] = (f32x4){0.f, 0.f, 0.f, 0.f};

    for (int k0 = 0; k0 < ND; k0 += 32) {
        __syncthreads();
        {
            uint4 h0, l0;
            splitpack(ra0, ra1, h0, l0);
            *(uint4*)&Ah[am * 32 + ak] = h0;
            *(uint4*)&Al[am * 32 + ak] = l0;
            *(uint4*)&Bh[bn * 32 + bk2] = rb0; *(uint4*)&Bh[bn * 32 + bk2 + 8] = rb1;
            if (which != 2) {
                *(uint4*)&Bl[bn * 32 + bk2] = rb2; *(uint4*)&Bl[bn * 32 + bk2 + 8] = rb3;
            }
        }
        __syncthreads();
        if (k0 + 32 < ND) {
            const size_t aN = aG + k0 + 32, bN = bG + k0 + 32;
            ra0 = *(const float4*)&A_g[aN];
            ra1 = *(const float4*)&A_g[aN + 4];
            rb0 = *(const uint4*)&Bh_g[bN];
            rb1 = *(const uint4*)&Bh_g[bN + 8];
            if (which != 2) {
                rb2 = *(const uint4*)&Bl_g[bN];
                rb3 = *(const uint4*)&Bl_g[bN + 8];
            }
        }

        bf16x8 ah[2], al2[2], bh[4], bl[4];
        #pragma unroll
        for (int mi = 0; mi < 2; ++mi) {
            const int ar = (wm * 32 + mi * 16 + lc) * 32 + quad * 8;
            ah[mi] = *(const bf16x8*)&Ah[ar];
            al2[mi] = *(const bf16x8*)&Al[ar];
        }
        #pragma unroll
        for (int ni = 0; ni < 4; ++ni) {
            const int br = (wn * 64 + ni * 16 + lc) * 32 + quad * 8;
            bh[ni] = *(const bf16x8*)&Bh[br];
            if (which != 2) bl[ni] = *(const bf16x8*)&Bl[br];
        }
        if (which != 2) {
            #pragma unroll
            for (int mi = 0; mi < 2; ++mi)
                #pragma unroll
                for (int ni = 0; ni < 4; ++ni) {
                    acc[mi][ni] = MFMA(al2[mi], bh[ni], acc[mi][ni]);
                    acc[mi][ni] = MFMA(ah[mi], bl[ni], acc[mi][ni]);
                    acc[mi][ni] = MFMA(ah[mi], bh[ni], acc[mi][ni]);
                }
        } else {
            #pragma unroll
            for (int mi = 0; mi < 2; ++mi)
                #pragma unroll
                for (int ni = 0; ni < 4; ++ni) {
                    acc[mi][ni] = MFMA(al2[mi], bh[ni], acc[mi][ni]);
                    acc[mi][ni] = MFMA(ah[mi], bh[ni], acc[mi][ni]);
                }
        }
    }

    // ---- epilogue ----
    const int bb = m0 >> 10, tt0 = m0 & 1023;
    const int hh = tt0 >> 7, cch0 = (tt0 & 127) >> 1;
    const int bh_idx = bb * NH + hh;

    if (which == 2) {   // v: tiled store [bh][t>>6][cch][t&63]
        #pragma unroll
        for (int ni = 0; ni < 4; ++ni) {
            const int n = n0 + wn * 64 + ni * 16 + lc;
            const float bval = bias[n];
            #pragma unroll
            for (int mi = 0; mi < 2; ++mi)
                #pragma unroll
                for (int r = 0; r < 4; ++r) {
                    const int mloc = wm * 32 + mi * 16 + quad * 4 + r;
                    const int cch = cch0 + (mloc >> 1);
                    const int t = (mloc & 1) * 512 + n;
                    vh_o[(((size_t)bh_idx * 16 + (t >> 6)) * 64 + cch) * 64 + (t & 63)] =
                        f2bu(acc[mi][ni][r] + bval);
                }
        }
        return;
    }

    const int npass = (which == 0) ? 2 : 1;
    unsigned short* outp[2] = {(which == 0) ? qh_o : kh_o, ql_o};

    for (int pass = 0; pass < npass; ++pass) {
        __syncthreads();
        #pragma unroll
        for (int ni = 0; ni < 4; ++ni) {
            const int nloc = wn * 64 + ni * 16 + lc;
            const float bval = bias[n0 + nloc];
            #pragma unroll
            for (int mi = 0; mi < 2; ++mi)
                #pragma unroll
                for (int r = 0; r < 4; ++r) {
                    const int mloc = wm * 32 + mi * 16 + quad * 4 + r;
                    const float val = acc[mi][ni][r] + bval;
                    unsigned short hs, ls;
                    if (which == 0) { split1(val, hs, ls); }
                    else { hs = f2bu(val); ls = 0; }
                    Tr[((mloc & 1) * 128 + nloc) * 40 + (mloc >> 1)] =
                        (pass == 0) ? hs : ls;
                }
        }
        __syncthreads();
        {
            const int t = (tid >> 7) * 512 + n0 + (tid & 127);
            const size_t oa = ((size_t)bh_idx * NT + t) * NKC + cch0;
            const uint4 v0 = *(const uint4*)&Tr[tid * 40];
            const uint4 v1 = *(const uint4*)&Tr[tid * 40 + 8];
            const uint4 v2 = *(const uint4*)&Tr[tid * 40 + 16];
            const uint4 v3 = *(const uint4*)&Tr[tid * 40 + 24];
            *(uint4*)&outp[pass][oa]      = v0;
            *(uint4*)&outp[pass][oa + 8]  = v1;
            *(uint4*)&outp[pass][oa + 16] = v2;
            *(uint4*)&outp[pass][oa + 24] = v3;
        }
    }
}

// ===========================================================================
// MFMA flash attention, s-split x2, no online softmax, depth-2 K/V prefetch.
// grid (32, 8, 4): x = qtile*2 + s-half. fp32 O-partial [bh][c][q], l [bh][q].
// ===========================================================================
__global__ __launch_bounds__(256, 4)
void attn_mfma(const unsigned short* __restrict__ qh_g, const unsigned short* __restrict__ ql_g,
               const unsigned short* __restrict__ kh_g,
               const unsigned short* __restrict__ vh_g,
               const float* __restrict__ embk, const float* __restrict__ embv,
               float* __restrict__ O0, float* __restrict__ O1,
               float* __restrict__ l0_g, float* __restrict__ l1_g)
{
    __shared__ unsigned short smem[19456];
    unsigned short* KsH = smem;                 // 64*72
    unsigned short* Vt  = smem + 4608;          // 64*104
    unsigned short* Ps  = smem + 11264;         // 4*16*104
    float* bandv = (float*)(smem + 17920);      // 64*12 f32
    unsigned short* EkH = smem + 11264;         // alias over Ps (preamble)

    const int tid = threadIdx.x, l = tid & 63, w = tid >> 6;
    const int quad = l >> 4, lc = l & 15;
    const int q0 = (blockIdx.x >> 1) * 64;
    const int sh = blockIdx.x & 1;
    const int sBeg = sh * 512;
    const int hh = blockIdx.y, bb = blockIdx.z;
    const int bh = bb * NH + hh;
    const size_t qkBase = (size_t)bh * NT * NKC;
    const size_t vtBase = (size_t)bh * (16 * 64 * 64);
    float* Op = sh ? O1 : O0;
    float* lp = sh ? l1_g : l0_g;

    const int srow = tid >> 2, sseg = (tid & 3) * 16;

    auto loadKV = [&](uint4& k0r, uint4& k1r, uint4& v0r, uint4& v1r, int tile) {
        const size_t ka = qkBase + (size_t)(sBeg + tile * 64 + srow) * NKC + sseg;
        const size_t va = vtBase + (size_t)((sBeg >> 6) + tile) * 4096 + srow * 64 + sseg;
        k0r = *(const uint4*)&kh_g[ka];
        k1r = *(const uint4*)&kh_g[ka + 8];
        v0r = *(const uint4*)&vh_g[va];
        v1r = *(const uint4*)&vh_g[va + 8];
    };

    // depth-2 prologue
    uint4 ak0, ak1, av0, av1, bk0, bk1, bv0, bv1;
    loadKV(ak0, ak1, av0, av1, 0);
    loadKV(bk0, bk1, bv0, bv1, 1);

    // stage emb_k hi [16][72] (rows 9..15 zero)
    for (int idx = tid; idx < 16 * 72; idx += 256) {
        const int d = idx / 72, kc = idx - d * 72;
        EkH[idx] = f2bu((d < 9 && kc < 64) ? embk[d * 64 + kc] : 0.f);
    }
    // stage Vt static cols 64..103: emb_v^T then zeros
    for (int idx = tid; idx < 64 * 40; idx += 256) {
        const int c = idx / 40, col = 64 + (idx - c * 40);
        const int d = col - 64;
        Vt[c * 104 + col] = f2bu((d < 9) ? embv[d * 64 + c] : 0.f);
    }
    __syncthreads();

    bf16x8 qh[2], ql[2];
    {
        const int qg = q0 + w * 16 + lc;
        const size_t qa = qkBase + (size_t)qg * NKC + quad * 8;
        qh[0] = *(const bf16x8*)&qh_g[qa];
        qh[1] = *(const bf16x8*)&qh_g[qa + 32];
        ql[0] = *(const bf16x8*)&ql_g[qa];
        ql[1] = *(const bf16x8*)&ql_g[qa + 32];
    }

    {   // band rel-k logits (single-bf16 emb_k)
        f32x4 accB = (f32x4){0.f, 0.f, 0.f, 0.f};
        #pragma unroll
        for (int kk = 0; kk < 2; ++kk) {
            const bf16x8 ebh = *(const bf16x8*)&EkH[lc * 72 + kk * 32 + quad * 8];
            accB = MFMA(ql[kk], ebh, accB);
            accB = MFMA(qh[kk], ebh, accB);
        }
        __syncthreads();
        if (lc <= 8) {
            #pragma unroll
            for (int r = 0; r < 4; ++r)
                bandv[(w * 16 + quad * 4 + r) * 12 + lc] = accB[r];
        }
    }
    unsigned short* P = Ps + w * 1664;
    {
        const int zr = l >> 2, zc = 80 + (l & 3) * 4;
        *(ushort4*)&P[zr * 104 + zc] = make_ushort4(0, 0, 0, 0);
    }

    f32x4 O[4];
    #pragma unroll
    for (int ci = 0; ci < 4; ++ci) O[ci] = (f32x4){0.f, 0.f, 0.f, 0.f};
    float l_run[4] = {0.f, 0.f, 0.f, 0.f};

    auto tilestep = [&](uint4& k0r, uint4& k1r, uint4& v0r, uint4& v1r,
                        int i, int nextTile) {
        const int s0 = sBeg + i * 64;
        __syncthreads();
        *(uint4*)&KsH[srow * 72 + sseg]      = k0r;
        *(uint4*)&KsH[srow * 72 + sseg + 8]  = k1r;
        *(uint4*)&Vt[srow * 104 + sseg]      = v0r;
        *(uint4*)&Vt[srow * 104 + sseg + 8]  = v1r;
        __syncthreads();
        if (nextTile >= 0) loadKV(k0r, k1r, v0r, v1r, nextTile);

        // ---- QK^T: (qh+ql) x K_bf16 ----
        f32x4 S[4];
        #pragma unroll
        for (int ni = 0; ni < 4; ++ni) {
            f32x4 a = (f32x4){0.f, 0.f, 0.f, 0.f};
            #pragma unroll
            for (int kk = 0; kk < 2; ++kk) {
                const bf16x8 kb = *(const bf16x8*)&KsH[(ni * 16 + lc) * 72 + kk * 32 + quad * 8];
                a = MFMA(ql[kk], kb, a);
                a = MFMA(qh[kk], kb, a);
            }
            S[ni] = a;
        }

        // ---- band add + scale + exp (no max subtraction; |S|<~6) ----
        #pragma unroll
        for (int ni = 0; ni < 4; ++ni)
            #pragma unroll
            for (int r = 0; r < 4; ++r) {
                const int ql64 = w * 16 + quad * 4 + r;
                const int dp4 = (s0 + ni * 16 + lc) - (q0 + ql64) + 4;
                float sv = S[ni][r];
                if (dp4 >= 0 && dp4 <= 8) sv += bandv[ql64 * 12 + dp4];
                S[ni][r] = __expf(sv * 0.125f);
            }
        #pragma unroll
        for (int r = 0; r < 4; ++r)
            l_run[r] += S[0][r] + S[1][r] + S[2][r] + S[3][r];

        // ---- P -> per-wave LDS (+ predicated band columns) ----
        {
            const int zr = l >> 2, zc = 64 + (l & 3) * 4;
            *(ushort4*)&P[zr * 104 + zc] = make_ushort4(0, 0, 0, 0);
        }
        #pragma unroll
        for (int ni = 0; ni < 4; ++ni)
            #pragma unroll
            for (int r = 0; r < 4; ++r) {
                const int prow = quad * 4 + r;
                const unsigned short pb = f2bu(S[ni][r]);
                P[prow * 104 + ni * 16 + lc] = pb;
                const int dp4 = (s0 + ni * 16 + lc) - (q0 + w * 16 + prow) + 4;
                if (dp4 >= 0 && dp4 <= 8) P[prow * 104 + 64 + dp4] = pb;
            }

        // ---- PV over extended k = 96 (V rows 64..72 = emb_v) ----
        #pragma unroll
        for (int ks = 0; ks < 3; ++ks) {
            const bf16x8 pa = *(const bf16x8*)&P[lc * 104 + ks * 32 + quad * 8];
            #pragma unroll
            for (int ci = 0; ci < 4; ++ci) {
                const bf16x8 vb = *(const bf16x8*)&Vt[(ci * 16 + lc) * 104 + ks * 32 + quad * 8];
                O[ci] = MFMA(pa, vb, O[ci]);
            }
        }
    };

    for (int ii = 0; ii < 8; ii += 2) {
        tilestep(ak0, ak1, av0, av1, ii,     (ii + 2 < 8) ? ii + 2 : -1);
        tilestep(bk0, bk1, bv0, bv1, ii + 1, (ii + 3 < 8) ? ii + 3 : -1);
    }

    // ---- epilogue: reduce l over the 16 col-lanes, store raw partials ----
    #pragma unroll
    for (int r = 0; r < 4; ++r) {
        float v = l_run[r];
        v += __shfl_xor(v, 1); v += __shfl_xor(v, 2);
        v += __shfl_xor(v, 4); v += __shfl_xor(v, 8);
        l_run[r] = v;
    }
    const int qg0 = q0 + w * 16 + quad * 4;
    if (lc == 0) {
        #pragma unroll
        for (int r = 0; r < 4; ++r)
            lp[(size_t)bh * NT + qg0 + r] = l_run[r];
    }
    #pragma unroll
    for (int ci = 0; ci < 4; ++ci) {
        const int c = ci * 16 + lc;
        *(f32x4*)&Op[((size_t)bh * 64 + c) * NT + qg0] = O[ci];
    }
}

// ===========================================================================
// Output projection fused with partial-combine: A[m][k] is built on the fly
// from (O0+O1)*linv (the q-normalization is a per-k column scale of A because
// the output reshape transposes t and channel). 64x64 tile, B = wo hi/lo.
// ===========================================================================
__global__ __launch_bounds__(256, 4)
void outproj_fused(const float* __restrict__ O0, const float* __restrict__ O1,
                   const float* __restrict__ l0_g, const float* __restrict__ l1_g,
                   const unsigned short* __restrict__ wTh,
                   const float* __restrict__ bo, float* __restrict__ out)
{
    __shared__ unsigned short As[64 * 32], Bh[64 * 32], Bl[64 * 32];
    __shared__ float linv[1024];
    const unsigned short* Bl_g = wTh + ND * ND;
    const int tid = threadIdx.x, l = tid & 63, w = tid >> 6;
    const int quad = l >> 4, lc = l & 15;
    const int wm = w & 1, wn = w >> 1;
    const int n0 = blockIdx.x * 64, m0 = blockIdx.y * 64;

    const int bb = m0 >> 10, hh = (m0 & 1023) >> 7;
    const int bh = bb * NH + hh;

    for (int i = tid; i < 1024; i += 256)
        linv[i] = 1.f / (l0_g[(size_t)bh * NT + i] + l1_g[(size_t)bh * NT + i]);

    // A staging map: row rl = sm -> c=((m0&127)+sm)>>1, tb=sm&1; 8 k's at sk
    const int sm = tid >> 2, sk = (tid & 3) * 8;
    const int cch = ((m0 & 127) + sm) >> 1, tb = sm & 1;
    const size_t oBase = ((size_t)bh * 64 + cch) * NT + tb * 512 + sk;
    const size_t bG = (size_t)(n0 + sm) * ND + sk;

    float4 ro0a = *(const float4*)&O0[oBase];
    float4 ro0b = *(const float4*)&O0[oBase + 4];
    float4 ro1a = *(const float4*)&O1[oBase];
    float4 ro1b = *(const float4*)&O1[oBase + 4];
    uint4 rbh = *(const uint4*)&wTh[bG];
    uint4 rbl = *(const uint4*)&Bl_g[bG];

    f32x4 acc[2][2];
    #pragma unroll
    for (int mi = 0; mi < 2; ++mi)
        #pragma unroll
        for (int ni = 0; ni < 2; ++ni) acc[mi][ni] = (f32x4){0.f, 0.f, 0.f, 0.f};

    for (int k0 = 0; k0 < ND; k0 += 32) {
        __syncthreads();
        {
            const float* lv = &linv[tb * 512 + k0 + sk];
            const float f[8] = {ro0a.x + ro1a.x, ro0a.y + ro1a.y,
                                ro0a.z + ro1a.z, ro0a.w + ro1a.w,
                                ro0b.x + ro1b.x, ro0b.y + ro1b.y,
                                ro0b.z + ro1b.z, ro0b.w + ro1b.w};
            union { unsigned short u[8]; uint4 v; } pk;
            #pragma unroll
            for (int j = 0; j < 8; ++j) pk.u[j] = f2bu(f[j] * lv[j]);
            *(uint4*)&As[sm * 32 + sk] = pk.v;
            *(uint4*)&Bh[sm * 32 + sk] = rbh;
            *(uint4*)&Bl[sm * 32 + sk] = rbl;
        }
        __syncthreads();
        if (k0 + 32 < ND) {
            ro0a = *(const float4*)&O0[oBase + k0 + 32];
            ro0b = *(const float4*)&O0[oBase + k0 + 36];
            ro1a = *(const float4*)&O1[oBase + k0 + 32];
            ro1b = *(const float4*)&O1[oBase + k0 + 36];
            rbh  = *(const uint4*)&wTh[bG + k0 + 32];
            rbl  = *(const uint4*)&Bl_g[bG + k0 + 32];
        }
        bf16x8 ab[2], bhf[2], blf[2];
        #pragma unroll
        for (int mi = 0; mi < 2; ++mi)
            ab[mi] = *(const bf16x8*)&As[(wm * 32 + mi * 16 + lc) * 32 + quad * 8];
        #pragma unroll
        for (int ni = 0; ni < 2; ++ni) {
            const int br = (wn * 32 + ni * 16 + lc) * 32 + quad * 8;
            bhf[ni] = *(const bf16x8*)&Bh[br];
            blf[ni] = *(const bf16x8*)&Bl[br];
        }
        #pragma unroll
        for (int mi = 0; mi < 2; ++mi)
            #pragma unroll
            for (int ni = 0; ni < 2; ++ni) {
                acc[mi][ni] = MFMA(ab[mi], bhf[ni], acc[mi][ni]);
                acc[mi][ni] = MFMA(ab[mi], blf[ni], acc[mi][ni]);
            }
    }

    #pragma unroll
    for (int ni = 0; ni < 2; ++ni) {
        const int n = n0 + wn * 32 + ni * 16 + lc;
        const float bval = bo[n];
        #pragma unroll
        for (int mi = 0; mi < 2; ++mi)
            #pragma unroll
            for (int r = 0; r < 4; ++r) {
                const int m = m0 + wm * 32 + mi * 16 + quad * 4 + r;
                out[(size_t)m * ND + n] = acc[mi][ni][r] + bval;
            }
    }
}

extern "C" void kernel_launch(void* const* d_in, const int* in_sizes, int n_in,
                              void* d_out, int out_size, void* d_ws, size_t ws_size,
                              hipStream_t stream) {
    const float* x    = (const float*)d_in[0];
    const float* c    = (const float*)d_in[1];
    const float* wq   = (const float*)d_in[2];
    const float* bq   = (const float*)d_in[3];
    const float* wk   = (const float*)d_in[4];
    const float* bk   = (const float*)d_in[5];
    const float* wv   = (const float*)d_in[6];
    const float* bv   = (const float*)d_in[7];
    const float* wo   = (const float*)d_in[8];
    const float* bo   = (const float*)d_in[9];
    const float* embk = (const float*)d_in[10];
    const float* embv = (const float*)d_in[11];

    unsigned short* u16 = (unsigned short*)d_ws;
    const size_t M = 1024 * 1024;
    unsigned short* wT  = u16;                 // 2M ush = 4MB
    unsigned short* qh  = u16 + 2 * M;
    unsigned short* ql  = u16 + 4 * M;
    unsigned short* kh  = u16 + 6 * M;
    unsigned short* vh  = u16 + 8 * M;         // tiled [bh][16][64][64]
    float* fbase = (float*)(u16 + 10 * M);
    float* O0   = fbase;                       // 2M f32 = 8MB
    float* O1   = fbase + 2 * M;               // 8MB
    float* l0_g = fbase + 4 * M;               // 128KB
    float* l1_g = l0_g + 32768;                // 128KB

    splitT_kernel<<<dim3(16, 16, 4), 256, 0, stream>>>(wq, wk, wv, wo, wT);

    proj_mfma<<<dim3(4, 64, 3), 256, 0, stream>>>(x, c, wT, bq, bk, bv,
                                                  qh, ql, kh, vh);

    attn_mfma<<<dim3(32, 8, 4), 256, 0, stream>>>(qh, ql, kh, vh,
                                                  embk, embv, O0, O1, l0_g, l1_g);

    outproj_fused<<<dim3(8, 64), 256, 0, stream>>>(O0, O1, l0_g, l1_g,
                                                   wT + (size_t)3 * 2 * ND * ND,
                                                   bo, (float*)d_out);
}

// Round 11
// 171.097 us; speedup vs baseline: 1.0002x; 1.0002x over previous
//
#include <hip/hip_runtime.h>
#include <hip/hip_bf16.h>

#define NB 4
#define NT 1024
#define ND 512
#define NH 8
#define NKC 64

typedef __bf16 bf16x8 __attribute__((ext_vector_type(8)));
typedef float f32x4 __attribute__((ext_vector_type(4)));

__device__ __forceinline__ f32x4 MFMA(bf16x8 a, bf16x8 b, f32x4 c) {
    return __builtin_amdgcn_mfma_f32_16x16x32_bf16(a, b, c, 0, 0, 0);
}
__device__ __forceinline__ unsigned short f2bu(float v) {
    __hip_bfloat16 b = __float2bfloat16(v);
    return *(unsigned short*)&b;
}
__device__ __forceinline__ void split1(float v, unsigned short& h, unsigned short& l)
{
    __hip_bfloat16 hb = __float2bfloat16(v);
    float r = v - __bfloat162float(hb);
    __hip_bfloat16 lb = __float2bfloat16(r);
    h = *(unsigned short*)&hb;
    l = *(unsigned short*)&lb;
}
__device__ __forceinline__ void splitpack(const float4 a, const float4 b, uint4& h, uint4& l)
{
    union { unsigned short u[8]; uint4 v; } H, L;
    const float f[8] = {a.x, a.y, a.z, a.w, b.x, b.y, b.z, b.w};
    #pragma unroll
    for (int j = 0; j < 8; ++j) split1(f[j], H.u[j], L.u[j]);
    h = H.v; l = L.v;
}

// w[k][n] fp32 -> wT hi/lo bf16 [n][k]
__global__ __launch_bounds__(256)
void splitT_kernel(const float* __restrict__ w0, const float* __restrict__ w1,
                   const float* __restrict__ w2, const float* __restrict__ w3,
                   unsigned short* __restrict__ wT)
{
    __shared__ float tl[32][33];
    const float* w = (blockIdx.z == 0) ? w0 : (blockIdx.z == 1) ? w1
                   : (blockIdx.z == 2) ? w2 : w3;
    unsigned short* hi = wT + (size_t)blockIdx.z * 2 * (ND * ND);
    unsigned short* lo = hi + ND * ND;
    const int t = threadIdx.x;
    const int x0 = blockIdx.x * 32, y0 = blockIdx.y * 32;
    {
        const int r = t >> 3, c = (t & 7) * 4;
        const float4 v = *(const float4*)&w[(size_t)(y0 + r) * ND + x0 + c];
        tl[r][c] = v.x; tl[r][c+1] = v.y; tl[r][c+2] = v.z; tl[r][c+3] = v.w;
    }
    __syncthreads();
    {
        const int nr = t >> 3, k4 = (t & 7) * 4;
        unsigned short hh[4], ll[4];
        #pragma unroll
        for (int j = 0; j < 4; ++j) split1(tl[k4 + j][nr], hh[j], ll[j]);
        ushort4 h = make_ushort4(hh[0], hh[1], hh[2], hh[3]);
        ushort4 l = make_ushort4(ll[0], ll[1], ll[2], ll[3]);
        *(ushort4*)&hi[(size_t)(x0 + nr) * ND + y0 + k4] = h;
        *(ushort4*)&lo[(size_t)(x0 + nr) * ND + y0 + k4] = l;
    }
}

// ===========================================================================
// Projections: 64(m) x 128(n) tile, BK=32. q -> hi/lo [bh][t][kc];
// k -> bf16 [bh][t][kc]; v -> bf16 TILED [bh][t>>6][kc][t&63].
// v-GEMM uses single-bf16 weights.
// ===========================================================================
__global__ __launch_bounds__(256, 3)
void proj_mfma(const float* __restrict__ x, const float* __restrict__ cc,
               const unsigned short* __restrict__ wT,
               const float* __restrict__ bq, const float* __restrict__ bk,
               const float* __restrict__ bv,
               unsigned short* __restrict__ qh_o, unsigned short* __restrict__ ql_o,
               unsigned short* __restrict__ kh_o, unsigned short* __restrict__ vh_o)
{
    __shared__ unsigned short smem[12288];           // 24 KB
    unsigned short* Ah = smem;
    unsigned short* Al = smem + 2048;
    unsigned short* Bh = smem + 4096;
    unsigned short* Bl = smem + 8192;
    unsigned short* Tr = smem;                       // alias: 256*40 = 10240

    const int which = blockIdx.z;
    const float* A_g = (which == 0) ? x : cc;
    const unsigned short* Bh_g = wT + (size_t)which * 2 * (ND * ND);
    const unsigned short* Bl_g = Bh_g + ND * ND;
    const float* bias = (which == 0) ? bq : (which == 1) ? bk : bv;

    const int tid = threadIdx.x, l = tid & 63, w = tid >> 6;
    const int quad = l >> 4, lc = l & 15;
    const int wm = w & 1, wn = w >> 1;
    const int n0 = blockIdx.x * 128, m0 = blockIdx.y * 64;

    const int am = tid >> 2, ak = (tid & 3) * 8;
    const size_t aG = (size_t)(m0 + am) * ND + ak;
    const int bn = tid >> 1, bk2 = (tid & 1) * 16;
    const size_t bG = (size_t)(n0 + bn) * ND + bk2;

    float4 ra0 = *(const float4*)&A_g[aG];
    float4 ra1 = *(const float4*)&A_g[aG + 4];
    uint4 rb0 = *(const uint4*)&Bh_g[bG];
    uint4 rb1 = *(const uint4*)&Bh_g[bG + 8];
    uint4 rb2 = {}, rb3 = {};
    if (which != 2) {
        rb2 = *(const uint4*)&Bl_g[bG];
        rb3 = *(const uint4*)&Bl_g[bG + 8];
    }

    f32x4 acc[2][4];
    #pragma unroll
    for (int mi = 0; mi < 2; ++mi)
        #pragma unroll
        for (int ni = 0; ni < 4; ++ni) acc[mi][ni] = (f32x4){0.f, 0.f, 0.f, 0.f};

    for (int k0 = 0; k0 < ND; k0 += 32) {
        __syncthreads();
        {
            uint4 h0, l0;
            splitpack(ra0, ra1, h0, l0);
            *(uint4*)&Ah[am * 32 + ak] = h0;
            *(uint4*)&Al[am * 32 + ak] = l0;
            *(uint4*)&Bh[bn * 32 + bk2] = rb0; *(uint4*)&Bh[bn * 32 + bk2 + 8] = rb1;
            if (which != 2) {
                *(uint4*)&Bl[bn * 32 + bk2] = rb2; *(uint4*)&Bl[bn * 32 + bk2 + 8] = rb3;
            }
        }
        __syncthreads();
        if (k0 + 32 < ND) {
            const size_t aN = aG + k0 + 32, bN = bG + k0 + 32;
            ra0 = *(const float4*)&A_g[aN];
            ra1 = *(const float4*)&A_g[aN + 4];
            rb0 = *(const uint4*)&Bh_g[bN];
            rb1 = *(const uint4*)&Bh_g[bN + 8];
            if (which != 2) {
                rb2 = *(const uint4*)&Bl_g[bN];
                rb3 = *(const uint4*)&Bl_g[bN + 8];
            }
        }

        bf16x8 ah[2], al2[2], bh[4], bl[4];
        #pragma unroll
        for (int mi = 0; mi < 2; ++mi) {
            const int ar = (wm * 32 + mi * 16 + lc) * 32 + quad * 8;
            ah[mi] = *(const bf16x8*)&Ah[ar];
            al2[mi] = *(const bf16x8*)&Al[ar];
        }
        #pragma unroll
        for (int ni = 0; ni < 4; ++ni) {
            const int br = (wn * 64 + ni * 16 + lc) * 32 + quad * 8;
            bh[ni] = *(const bf16x8*)&Bh[br];
            if (which != 2) bl[ni] = *(const bf16x8*)&Bl[br];
        }
        if (which != 2) {
            #pragma unroll
            for (int mi = 0; mi < 2; ++mi)
                #pragma unroll
                for (int ni = 0; ni < 4; ++ni) {
                    acc[mi][ni] = MFMA(al2[mi], bh[ni], acc[mi][ni]);
                    acc[mi][ni] = MFMA(ah[mi], bl[ni], acc[mi][ni]);
                    acc[mi][ni] = MFMA(ah[mi], bh[ni], acc[mi][ni]);
                }
        } else {
            #pragma unroll
            for (int mi = 0; mi < 2; ++mi)
                #pragma unroll
                for (int ni = 0; ni < 4; ++ni) {
                    acc[mi][ni] = MFMA(al2[mi], bh[ni], acc[mi][ni]);
                    acc[mi][ni] = MFMA(ah[mi], bh[ni], acc[mi][ni]);
                }
        }
    }

    // ---- epilogue ----
    const int bb = m0 >> 10, tt0 = m0 & 1023;
    const int hh = tt0 >> 7, cch0 = (tt0 & 127) >> 1;
    const int bh_idx = bb * NH + hh;

    if (which == 2) {   // v: tiled store [bh][t>>6][cch][t&63]
        #pragma unroll
        for (int ni = 0; ni < 4; ++ni) {
            const int n = n0 + wn * 64 + ni * 16 + lc;
            const float bval = bias[n];
            #pragma unroll
            for (int mi = 0; mi < 2; ++mi)
                #pragma unroll
                for (int r = 0; r < 4; ++r) {
                    const int mloc = wm * 32 + mi * 16 + quad * 4 + r;
                    const int cch = cch0 + (mloc >> 1);
                    const int t = (mloc & 1) * 512 + n;
                    vh_o[(((size_t)bh_idx * 16 + (t >> 6)) * 64 + cch) * 64 + (t & 63)] =
                        f2bu(acc[mi][ni][r] + bval);
                }
        }
        return;
    }

    const int npass = (which == 0) ? 2 : 1;
    unsigned short* outp[2] = {(which == 0) ? qh_o : kh_o, ql_o};

    for (int pass = 0; pass < npass; ++pass) {
        __syncthreads();
        #pragma unroll
        for (int ni = 0; ni < 4; ++ni) {
            const int nloc = wn * 64 + ni * 16 + lc;
            const float bval = bias[n0 + nloc];
            #pragma unroll
            for (int mi = 0; mi < 2; ++mi)
                #pragma unroll
                for (int r = 0; r < 4; ++r) {
                    const int mloc = wm * 32 + mi * 16 + quad * 4 + r;
                    const float val = acc[mi][ni][r] + bval;
                    unsigned short hs, ls;
                    if (which == 0) { split1(val, hs, ls); }
                    else { hs = f2bu(val); ls = 0; }
                    Tr[((mloc & 1) * 128 + nloc) * 40 + (mloc >> 1)] =
                        (pass == 0) ? hs : ls;
                }
        }
        __syncthreads();
        {
            const int t = (tid >> 7) * 512 + n0 + (tid & 127);
            const size_t oa = ((size_t)bh_idx * NT + t) * NKC + cch0;
            const uint4 v0 = *(const uint4*)&Tr[tid * 40];
            const uint4 v1 = *(const uint4*)&Tr[tid * 40 + 8];
            const uint4 v2 = *(const uint4*)&Tr[tid * 40 + 16];
            const uint4 v3 = *(const uint4*)&Tr[tid * 40 + 24];
            *(uint4*)&outp[pass][oa]      = v0;
            *(uint4*)&outp[pass][oa + 8]  = v1;
            *(uint4*)&outp[pass][oa + 16] = v2;
            *(uint4*)&outp[pass][oa + 24] = v3;
        }
    }
}

// ===========================================================================
// MFMA flash attention v2: 128-row q-tile (2 subtiles serial per wave),
// s-split x2, no online softmax, depth-2 K/V prefetch, LDS-transposed
// coalesced O-partial stores. grid (16, 8, 4): x = qpair*2 + s-half.
// LDS (ushorts): KsH[64*72] | Vt[64*104] | Ps[4*16*104] | bandv f32[128*12]
// ===========================================================================
__global__ __launch_bounds__(256, 2)
void attn_mfma(const unsigned short* __restrict__ qh_g, const unsigned short* __restrict__ ql_g,
               const unsigned short* __restrict__ kh_g,
               const unsigned short* __restrict__ vh_g,
               const float* __restrict__ embk, const float* __restrict__ embv,
               float* __restrict__ O0, float* __restrict__ O1,
               float* __restrict__ l0_g, float* __restrict__ l1_g)
{
    __shared__ unsigned short smem[20992];
    unsigned short* KsH = smem;                 // 64*72
    unsigned short* Vt  = smem + 4608;          // 64*104
    unsigned short* Ps  = smem + 11264;         // 4*16*104
    float* bandv = (float*)(smem + 17920);      // 128*12 f32 = 3072 ush
    unsigned short* EkH = smem + 11264;         // alias over Ps (preamble)

    const int tid = threadIdx.x, l = tid & 63, w = tid >> 6;
    const int quad = l >> 4, lc = l & 15;
    const int q0 = (blockIdx.x >> 1) * 128;
    const int sh = blockIdx.x & 1;
    const int sBeg = sh * 512;
    const int hh = blockIdx.y, bb = blockIdx.z;
    const int bh = bb * NH + hh;
    const size_t qkBase = (size_t)bh * NT * NKC;
    const size_t vtBase = (size_t)bh * (16 * 64 * 64);
    float* Op = sh ? O1 : O0;
    float* lp = sh ? l1_g : l0_g;

    const int srow = tid >> 2, sseg = (tid & 3) * 16;

    auto loadKV = [&](uint4& k0r, uint4& k1r, uint4& v0r, uint4& v1r, int tile) {
        const size_t ka = qkBase + (size_t)(sBeg + tile * 64 + srow) * NKC + sseg;
        const size_t va = vtBase + (size_t)((sBeg >> 6) + tile) * 4096 + srow * 64 + sseg;
        k0r = *(const uint4*)&kh_g[ka];
        k1r = *(const uint4*)&kh_g[ka + 8];
        v0r = *(const uint4*)&vh_g[va];
        v1r = *(const uint4*)&vh_g[va + 8];
    };

    uint4 ak0, ak1, av0, av1, bk0, bk1, bv0, bv1;
    loadKV(ak0, ak1, av0, av1, 0);
    loadKV(bk0, bk1, bv0, bv1, 1);

    // stage emb_k hi [16][72]
    for (int idx = tid; idx < 16 * 72; idx += 256) {
        const int d = idx / 72, kc = idx - d * 72;
        EkH[idx] = f2bu((d < 9 && kc < 64) ? embk[d * 64 + kc] : 0.f);
    }
    // stage Vt static cols 64..103
    for (int idx = tid; idx < 64 * 40; idx += 256) {
        const int c = idx / 40, col = 64 + (idx - c * 40);
        const int d = col - 64;
        Vt[c * 104 + col] = f2bu((d < 9) ? embv[d * 64 + c] : 0.f);
    }
    __syncthreads();

    // Q fragments for both subtiles
    bf16x8 qh[2][2], ql[2][2];
    #pragma unroll
    for (int j = 0; j < 2; ++j) {
        const int qg = q0 + j * 64 + w * 16 + lc;
        const size_t qa = qkBase + (size_t)qg * NKC + quad * 8;
        qh[j][0] = *(const bf16x8*)&qh_g[qa];
        qh[j][1] = *(const bf16x8*)&qh_g[qa + 32];
        ql[j][0] = *(const bf16x8*)&ql_g[qa];
        ql[j][1] = *(const bf16x8*)&ql_g[qa + 32];
    }

    // band rel-k logits for both subtiles
    {
        f32x4 accB[2];
        #pragma unroll
        for (int j = 0; j < 2; ++j) {
            accB[j] = (f32x4){0.f, 0.f, 0.f, 0.f};
            #pragma unroll
            for (int kk = 0; kk < 2; ++kk) {
                const bf16x8 ebh = *(const bf16x8*)&EkH[lc * 72 + kk * 32 + quad * 8];
                accB[j] = MFMA(ql[j][kk], ebh, accB[j]);
                accB[j] = MFMA(qh[j][kk], ebh, accB[j]);
            }
        }
        __syncthreads();   // EkH reads done before Ps reuse
        if (lc <= 8) {
            #pragma unroll
            for (int j = 0; j < 2; ++j)
                #pragma unroll
                for (int r = 0; r < 4; ++r)
                    bandv[(j * 64 + w * 16 + quad * 4 + r) * 12 + lc] = accB[j][r];
        }
    }
    unsigned short* P = Ps + w * 1664;
    {
        const int zr = l >> 2, zc = 80 + (l & 3) * 4;
        *(ushort4*)&P[zr * 104 + zc] = make_ushort4(0, 0, 0, 0);
    }

    f32x4 O[2][4];
    #pragma unroll
    for (int j = 0; j < 2; ++j)
        #pragma unroll
        for (int ci = 0; ci < 4; ++ci) O[j][ci] = (f32x4){0.f, 0.f, 0.f, 0.f};
    float l_run[2][4] = {};

    auto tilestep = [&](uint4& k0r, uint4& k1r, uint4& v0r, uint4& v1r,
                        int i, int nextTile) {
        const int s0 = sBeg + i * 64;
        __syncthreads();
        *(uint4*)&KsH[srow * 72 + sseg]      = k0r;
        *(uint4*)&KsH[srow * 72 + sseg + 8]  = k1r;
        *(uint4*)&Vt[srow * 104 + sseg]      = v0r;
        *(uint4*)&Vt[srow * 104 + sseg + 8]  = v1r;
        __syncthreads();
        if (nextTile >= 0) loadKV(k0r, k1r, v0r, v1r, nextTile);

        #pragma unroll
        for (int j = 0; j < 2; ++j) {
            // ---- QK^T ----
            f32x4 S[4];
            #pragma unroll
            for (int ni = 0; ni < 4; ++ni) {
                f32x4 a = (f32x4){0.f, 0.f, 0.f, 0.f};
                #pragma unroll
                for (int kk = 0; kk < 2; ++kk) {
                    const bf16x8 kb = *(const bf16x8*)&KsH[(ni * 16 + lc) * 72 + kk * 32 + quad * 8];
                    a = MFMA(ql[j][kk], kb, a);
                    a = MFMA(qh[j][kk], kb, a);
                }
                S[ni] = a;
            }

            // ---- band add + scale + exp ----
            #pragma unroll
            for (int ni = 0; ni < 4; ++ni)
                #pragma unroll
                for (int r = 0; r < 4; ++r) {
                    const int ql128 = j * 64 + w * 16 + quad * 4 + r;
                    const int dp4 = (s0 + ni * 16 + lc) - (q0 + ql128) + 4;
                    float sv = S[ni][r];
                    if (dp4 >= 0 && dp4 <= 8) sv += bandv[ql128 * 12 + dp4];
                    S[ni][r] = __expf(sv * 0.125f);
                }
            #pragma unroll
            for (int r = 0; r < 4; ++r)
                l_run[j][r] += S[0][r] + S[1][r] + S[2][r] + S[3][r];

            // ---- P -> per-wave LDS (band-scratch re-zeroed per subtile) ----
            {
                const int zr = l >> 2, zc = 64 + (l & 3) * 4;
                *(ushort4*)&P[zr * 104 + zc] = make_ushort4(0, 0, 0, 0);
            }
            #pragma unroll
            for (int ni = 0; ni < 4; ++ni)
                #pragma unroll
                for (int r = 0; r < 4; ++r) {
                    const int prow = quad * 4 + r;
                    const unsigned short pb = f2bu(S[ni][r]);
                    P[prow * 104 + ni * 16 + lc] = pb;
                    const int dp4 = (s0 + ni * 16 + lc) - (q0 + j * 64 + w * 16 + prow) + 4;
                    if (dp4 >= 0 && dp4 <= 8) P[prow * 104 + 64 + dp4] = pb;
                }

            // ---- PV over extended k = 96 ----
            #pragma unroll
            for (int ks = 0; ks < 3; ++ks) {
                const bf16x8 pa = *(const bf16x8*)&P[lc * 104 + ks * 32 + quad * 8];
                #pragma unroll
                for (int ci = 0; ci < 4; ++ci) {
                    const bf16x8 vb = *(const bf16x8*)&Vt[(ci * 16 + lc) * 104 + ks * 32 + quad * 8];
                    O[j][ci] = MFMA(pa, vb, O[j][ci]);
                }
            }
        }
    };

    for (int ii = 0; ii < 8; ii += 2) {
        tilestep(ak0, ak1, av0, av1, ii,     (ii + 2 < 8) ? ii + 2 : -1);
        tilestep(bk0, bk1, bv0, bv1, ii + 1, (ii + 3 < 8) ? ii + 3 : -1);
    }

    // ---- epilogue: l reduce + LDS-transposed coalesced O stores ----
    float* Os = (float*)smem;   // [64][68] f32 = 17408 B, aliases staging bufs
    #pragma unroll
    for (int j = 0; j < 2; ++j) {
        #pragma unroll
        for (int r = 0; r < 4; ++r) {
            float v = l_run[j][r];
            v += __shfl_xor(v, 1); v += __shfl_xor(v, 2);
            v += __shfl_xor(v, 4); v += __shfl_xor(v, 8);
            l_run[j][r] = v;
        }
        const int qg0 = q0 + j * 64 + w * 16 + quad * 4;
        if (lc == 0) {
            #pragma unroll
            for (int r = 0; r < 4; ++r)
                lp[(size_t)bh * NT + qg0 + r] = l_run[j][r];
        }
        __syncthreads();   // previous smem use complete
        #pragma unroll
        for (int ci = 0; ci < 4; ++ci)
            #pragma unroll
            for (int r = 0; r < 4; ++r)
                Os[(ci * 16 + lc) * 68 + w * 16 + quad * 4 + r] = O[j][ci][r];
        __syncthreads();
        {
            const int c = tid >> 2, q4 = (tid & 3) * 16;
            const size_t ob = ((size_t)bh * 64 + c) * NT + q0 + j * 64 + q4;
            #pragma unroll
            for (int i4 = 0; i4 < 16; i4 += 4)
                *(f32x4*)&Op[ob + i4] = *(const f32x4*)&Os[c * 68 + q4 + i4];
        }
    }
}

// ===========================================================================
// Combine halves: att = (O0+O1)/(l0+l1), bf16, scramble store.
// ===========================================================================
__global__ __launch_bounds__(256)
void combine_kernel(const float* __restrict__ O0, const float* __restrict__ O1,
                    const float* __restrict__ l0_g, const float* __restrict__ l1_g,
                    unsigned short* __restrict__ ath)
{
    const int q0 = blockIdx.x * 64, hh = blockIdx.y, bb = blockIdx.z;
    const int bh = bb * NH + hh;
    const int tid = threadIdx.x;
    __shared__ float linv[64];
    if (tid < 64)
        linv[tid] = 1.f / (l0_g[(size_t)bh * NT + q0 + tid] +
                           l1_g[(size_t)bh * NT + q0 + tid]);
    __syncthreads();

    const int c = tid >> 2, qq = (tid & 3) * 16;
    const size_t ib = ((size_t)bh * 64 + c) * NT + q0 + qq;
    union { unsigned short u[16]; uint4 v[2]; } out;
    #pragma unroll
    for (int j = 0; j < 16; j += 4) {
        const f32x4 a = *(const f32x4*)&O0[ib + j];
        const f32x4 b = *(const f32x4*)&O1[ib + j];
        #pragma unroll
        for (int r = 0; r < 4; ++r)
            out.u[j + r] = f2bu((a[r] + b[r]) * linv[qq + j + r]);
    }
    const int row = hh * 128 + 2 * c + (q0 >> 9);
    const size_t oa = ((size_t)bb * NT + row) * ND + (q0 & 511) + qq;
    *(uint4*)&ath[oa]     = out.v[0];
    *(uint4*)&ath[oa + 8] = out.v[1];
}

// ===========================================================================
// Output projection: 64x64 tile, A = att single bf16, B = wo hi/lo.
// ===========================================================================
__global__ __launch_bounds__(256, 4)
void outproj_mfma(const unsigned short* __restrict__ a_g,
                  const unsigned short* __restrict__ wTh,
                  const float* __restrict__ bo, float* __restrict__ out)
{
    __shared__ unsigned short As[64 * 32], Bh[64 * 32], Bl[64 * 32];
    const unsigned short* Bl_g = wTh + ND * ND;
    const int tid = threadIdx.x, l = tid & 63, w = tid >> 6;
    const int quad = l >> 4, lc = l & 15;
    const int wm = w & 1, wn = w >> 1;
    const int n0 = blockIdx.x * 64, m0 = blockIdx.y * 64;

    const int sm = tid >> 2, sk = (tid & 3) * 8;
    const size_t aG = (size_t)(m0 + sm) * ND + sk;
    const size_t bG = (size_t)(n0 + sm) * ND + sk;

    uint4 ra  = *(const uint4*)&a_g[aG];
    uint4 rbh = *(const uint4*)&wTh[bG];
    uint4 rbl = *(const uint4*)&Bl_g[bG];

    f32x4 acc[2][2];
    #pragma unroll
    for (int mi = 0; mi < 2; ++mi)
        #pragma unroll
        for (int ni = 0; ni < 2; ++ni) acc[mi][ni] = (f32x4){0.f, 0.f, 0.f, 0.f};

    for (int k0 = 0; k0 < ND; k0 += 32) {
        __syncthreads();
        *(uint4*)&As[sm * 32 + sk] = ra;
        *(uint4*)&Bh[sm * 32 + sk] = rbh;
        *(uint4*)&Bl[sm * 32 + sk] = rbl;
        __syncthreads();
        if (k0 + 32 < ND) {
            ra  = *(const uint4*)&a_g[aG + k0 + 32];
            rbh = *(const uint4*)&wTh[bG + k0 + 32];
            rbl = *(const uint4*)&Bl_g[bG + k0 + 32];
        }
        bf16x8 ab[2], bhf[2], blf[2];
        #pragma unroll
        for (int mi = 0; mi < 2; ++mi)
            ab[mi] = *(const bf16x8*)&As[(wm * 32 + mi * 16 + lc) * 32 + quad * 8];
        #pragma unroll
        for (int ni = 0; ni < 2; ++ni) {
            const int br = (wn * 32 + ni * 16 + lc) * 32 + quad * 8;
            bhf[ni] = *(const bf16x8*)&Bh[br];
            blf[ni] = *(const bf16x8*)&Bl[br];
        }
        #pragma unroll
        for (int mi = 0; mi < 2; ++mi)
            #pragma unroll
            for (int ni = 0; ni < 2; ++ni) {
                acc[mi][ni] = MFMA(ab[mi], bhf[ni], acc[mi][ni]);
                acc[mi][ni] = MFMA(ab[mi], blf[ni], acc[mi][ni]);
            }
    }

    #pragma unroll
    for (int ni = 0; ni < 2; ++ni) {
        const int n = n0 + wn * 32 + ni * 16 + lc;
        const float bval = bo[n];
        #pragma unroll
        for (int mi = 0; mi < 2; ++mi)
            #pragma unroll
            for (int r = 0; r < 4; ++r) {
                const int m = m0 + wm * 32 + mi * 16 + quad * 4 + r;
                out[(size_t)m * ND + n] = acc[mi][ni][r] + bval;
            }
    }
}

extern "C" void kernel_launch(void* const* d_in, const int* in_sizes, int n_in,
                              void* d_out, int out_size, void* d_ws, size_t ws_size,
                              hipStream_t stream) {
    const float* x    = (const float*)d_in[0];
    const float* c    = (const float*)d_in[1];
    const float* wq   = (const float*)d_in[2];
    const float* bq   = (const float*)d_in[3];
    const float* wk   = (const float*)d_in[4];
    const float* bk   = (const float*)d_in[5];
    const float* wv   = (const float*)d_in[6];
    const float* bv   = (const float*)d_in[7];
    const float* wo   = (const float*)d_in[8];
    const float* bo   = (const float*)d_in[9];
    const float* embk = (const float*)d_in[10];
    const float* embv = (const float*)d_in[11];

    unsigned short* u16 = (unsigned short*)d_ws;
    const size_t M = 1024 * 1024;
    unsigned short* wT  = u16;                 // 2M ush = 4MB
    unsigned short* qh  = u16 + 2 * M;
    unsigned short* ql  = u16 + 4 * M;
    unsigned short* kh  = u16 + 6 * M;
    unsigned short* vh  = u16 + 8 * M;         // tiled [bh][16][64][64]
    unsigned short* ath = u16 + 10 * M;        // 12M ush = 24MB
    float* fbase = (float*)(u16 + 12 * M);
    float* O0   = fbase;                       // 8MB, [bh][c][q]
    float* O1   = fbase + 2 * M;               // 8MB
    float* l0_g = fbase + 4 * M;
    float* l1_g = l0_g + 32768;

    splitT_kernel<<<dim3(16, 16, 4), 256, 0, stream>>>(wq, wk, wv, wo, wT);

    proj_mfma<<<dim3(4, 64, 3), 256, 0, stream>>>(x, c, wT, bq, bk, bv,
                                                  qh, ql, kh, vh);

    attn_mfma<<<dim3(16, 8, 4), 256, 0, stream>>>(qh, ql, kh, vh,
                                                  embk, embv, O0, O1, l0_g, l1_g);

    combine_kernel<<<dim3(16, 8, 4), 256, 0, stream>>>(O0, O1, l0_g, l1_g, ath);

    outproj_mfma<<<dim3(8, 64), 256, 0, stream>>>(ath,
                                                  wT + (size_t)3 * 2 * ND * ND,
                                                  bo, (float*)d_out);
}